// Round 1
// 471.483 us; speedup vs baseline: 1.1192x; 1.1192x over previous
//
#include <hip/hip_runtime.h>
#include <hip/hip_bf16.h>
#include <math.h>

#define BATCH 2
#define RES   32
#define LTOK  32768          // RES^3
#define CDIM  288
#define NQKV  864
#define MROWS 65536          // BATCH*LTOK

typedef unsigned short u16;
typedef u16   u16x4 __attribute__((ext_vector_type(4)));
typedef short s16x8 __attribute__((ext_vector_type(8)));   // 8 bf16 in 4 VGPRs (MFMA A/B frag)
typedef float f32x4 __attribute__((ext_vector_type(4)));   // MFMA C/D frag

__device__ __forceinline__ u16 f2bf(float f) {
  union { __hip_bfloat16 h; u16 u; } x;
  x.h = __float2bfloat16(f);
  return x.u;
}
__device__ __forceinline__ float bf2f(u16 u) {
  union { u16 u; __hip_bfloat16 h; } x;
  x.u = u;
  return __bfloat162float(x.h);
}
// bf16 pair unpack from packed u32 (lo = even channel, hi = odd channel)
__device__ __forceinline__ float bflo(unsigned u) {
  union { unsigned u; float f; } x; x.u = u << 16; return x.f;
}
__device__ __forceinline__ float bfhi(unsigned u) {
  union { unsigned u; float f; } x; x.u = u & 0xffff0000u; return x.f;
}

// ---------------- weight transpose+convert: W (K x N) f32 -> Wt (N x K) bf16 ----------------
__global__ __launch_bounds__(256) void transpose_cvt(
    const float* __restrict__ w, u16* __restrict__ wt, int K, int N) {
  int o = blockIdx.x * 256 + threadIdx.x;
  if (o >= N * K) return;
  int n = o / K, k = o - n * K;
  wt[o] = f2bf(w[(size_t)k * N + n]);
}

// ---------------- bf16 MFMA GEMM: out = A(f32, MxK) @ Bt(bf16, NxK)^T (+bias) ----------------
// 128x128 tile, BK=96 (3 outer iters for K=288), register-prefetch double buffer,
// XCD-swizzled linear grid (blocks sharing an A stripe -> same XCD L2).
// LDS row stride 104 halves = 208 B: 16B-aligned, bank-start spread (2-way = free).
template <bool BF16OUT>
__global__ __launch_bounds__(256) void gemm_mfma(
    const float* __restrict__ A, const u16* __restrict__ Bt,
    const float* __restrict__ bias, void* __restrict__ out,
    int N, int K, int NX) {
  __shared__ __align__(16) u16 as[128 * 104];
  __shared__ __align__(16) u16 bs[128 * 104];
  // swizzle: NY divisible by 8; 8 consecutive by-blocks share bx group & XCD
  const int bid = blockIdx.x;
  const int grp = bid / (8 * NX), rr = bid % (8 * NX);
  const int by = grp * 8 + (rr & 7), bx = rr >> 3;
  const int bm = by * 128, bn = bx * 128;
  const int tid = threadIdx.x;
  const int lane = tid & 63, wave = tid >> 6;
  const int m16 = lane & 15, kq = lane >> 4;
  const int wm = (wave >> 1) * 64, wn = (wave & 1) * 64;

  // staging decompositions (constant per thread)
  int a_row[12], a_c4[12];
#pragma unroll
  for (int i = 0; i < 12; i++) { int s = tid + i * 256; a_row[i] = s / 24; a_c4[i] = s % 24; }
  int b_n[6], b_c8[6];
#pragma unroll
  for (int i = 0; i < 6; i++) { int s = tid + i * 256; b_n[i] = s / 12; b_c8[i] = s % 12; }

  float4 pa[12];
  uint4  pb[6];
#pragma unroll
  for (int i = 0; i < 12; i++)
    pa[i] = *(const float4*)(A + (size_t)(bm + a_row[i]) * K + a_c4[i] * 4);
#pragma unroll
  for (int i = 0; i < 6; i++) {
    int gn = bn + b_n[i];
    pb[i] = (gn < N) ? *(const uint4*)(Bt + (size_t)gn * K + b_c8[i] * 8)
                     : make_uint4(0u, 0u, 0u, 0u);
  }

  f32x4 acc[4][4];
#pragma unroll
  for (int i = 0; i < 4; i++)
#pragma unroll
    for (int j = 0; j < 4; j++) acc[i][j] = (f32x4){0.f, 0.f, 0.f, 0.f};

  const int NIT = K / 96;
  for (int it = 0; it < NIT; it++) {
    // stage prefetched regs -> LDS
#pragma unroll
    for (int i = 0; i < 12; i++) {
      u16x4 p;
      p[0] = f2bf(pa[i].x); p[1] = f2bf(pa[i].y);
      p[2] = f2bf(pa[i].z); p[3] = f2bf(pa[i].w);
      *(u16x4*)&as[a_row[i] * 104 + a_c4[i] * 4] = p;
    }
#pragma unroll
    for (int i = 0; i < 6; i++)
      *(uint4*)&bs[b_n[i] * 104 + b_c8[i] * 8] = pb[i];
    __syncthreads();
    // prefetch next K-chunk (latency hides under compute below)
    if (it + 1 < NIT) {
      int k0 = (it + 1) * 96;
#pragma unroll
      for (int i = 0; i < 12; i++)
        pa[i] = *(const float4*)(A + (size_t)(bm + a_row[i]) * K + k0 + a_c4[i] * 4);
#pragma unroll
      for (int i = 0; i < 6; i++) {
        int gn = bn + b_n[i];
        pb[i] = (gn < N) ? *(const uint4*)(Bt + (size_t)gn * K + k0 + b_c8[i] * 8)
                         : make_uint4(0u, 0u, 0u, 0u);
      }
    }
#pragma unroll
    for (int ks = 0; ks < 3; ks++) {
      const int ko = ks * 32 + kq * 8;
      s16x8 af[4], bfr[4];
#pragma unroll
      for (int mi = 0; mi < 4; mi++)
        af[mi] = *(s16x8*)&as[(wm + mi * 16 + m16) * 104 + ko];
#pragma unroll
      for (int ni = 0; ni < 4; ni++)
        bfr[ni] = *(s16x8*)&bs[(wn + ni * 16 + m16) * 104 + ko];
#pragma unroll
      for (int mi = 0; mi < 4; mi++)
#pragma unroll
        for (int ni = 0; ni < 4; ni++)
          acc[mi][ni] = __builtin_amdgcn_mfma_f32_16x16x32_bf16(
              af[mi], bfr[ni], acc[mi][ni], 0, 0, 0);
    }
    __syncthreads();
  }
  // epilogue: C/D layout col=lane&15, row=quad*4+reg
#pragma unroll
  for (int mi = 0; mi < 4; mi++) {
#pragma unroll
    for (int ni = 0; ni < 4; ni++) {
      int col = bn + wn + ni * 16 + m16;
      if (col >= N) continue;
      float bv = bias ? bias[col] : 0.f;
#pragma unroll
      for (int r = 0; r < 4; r++) {
        int row = bm + wm + mi * 16 + kq * 4 + r;
        float v = acc[mi][ni][r] + bv;
        if (BF16OUT)
          ((u16*)out)[(size_t)row * N + col] = f2bf(v);
        else
          ((float*)out)[(size_t)row * N + col] = v;
      }
    }
  }
}

// ---------------- tiny RPE-bias MLP: (3,63,3) -> (3,63,4) ----------------
__device__ __forceinline__ void ln_relu6(const float* x, float* o,
                                         const float* g, const float* b) {
  float m = 0.f;
#pragma unroll
  for (int i = 0; i < 6; i++) m += x[i];
  m *= (1.f / 6.f);
  float v = 0.f;
#pragma unroll
  for (int i = 0; i < 6; i++) { float d = x[i] - m; v += d * d; }
  v *= (1.f / 6.f);
  float r = rsqrtf(v + 1e-5f);
#pragma unroll
  for (int i = 0; i < 6; i++) {
    float t = (x[i] - m) * r * g[i] + b[i];
    o[i] = t > 0.f ? t : 0.f;
  }
}

__global__ __launch_bounds__(256) void rpe_mlp(
    const float* __restrict__ rpe, const float* __restrict__ pw, const float* __restrict__ pb,
    const float* __restrict__ g1, const float* __restrict__ b1,
    const float* __restrict__ w1, const float* __restrict__ bb1,
    const float* __restrict__ g2, const float* __restrict__ b2,
    const float* __restrict__ w2, const float* __restrict__ bb2,
    const float* __restrict__ g3, const float* __restrict__ b3,
    const float* __restrict__ w3, const float* __restrict__ bb3,
    float* __restrict__ ptab) {
  int t = blockIdx.x * blockDim.x + threadIdx.x;
  if (t >= 3 * 63) return;
  int bi = t / 63, row = t % 63;
  float p[6], q[6];
#pragma unroll
  for (int j = 0; j < 6; j++) {
    float s = pb[bi * 6 + j];
#pragma unroll
    for (int i = 0; i < 3; i++) s += rpe[(bi * 63 + row) * 3 + i] * pw[(bi * 3 + i) * 6 + j];
    p[j] = s;
  }
  ln_relu6(p, q, g1 + bi * 6, b1 + bi * 6);
#pragma unroll
  for (int j = 0; j < 6; j++) {
    float s = bb1[bi * 6 + j];
#pragma unroll
    for (int i = 0; i < 6; i++) s += q[i] * w1[(bi * 6 + i) * 6 + j];
    p[j] = s;
  }
  ln_relu6(p, q, g2 + bi * 6, b2 + bi * 6);
#pragma unroll
  for (int j = 0; j < 6; j++) {
    float s = bb2[bi * 6 + j];
#pragma unroll
    for (int i = 0; i < 6; i++) s += q[i] * w2[(bi * 6 + i) * 6 + j];
    p[j] = s;
  }
  ln_relu6(p, q, g3 + bi * 6, b3 + bi * 6);
#pragma unroll
  for (int h = 0; h < 4; h++) {
    float s = bb3[bi * 4 + h];
#pragma unroll
    for (int i = 0; i < 6; i++) s += q[i] * w3[(bi * 6 + i) * 4 + h];
    ptab[(bi * 63 + row) * 4 + h] = s;
  }
}

// ---------------- windowed attention: one wave per window ----------------
// qkv layout (bf16): (b*L, 864) with column = s*288 + bi*96 + c.  y (f32): (b*L, 288).
__global__ __launch_bounds__(64) void attn_kernel(
    const u16* __restrict__ qkv, const float* __restrict__ ptab,
    const int* __restrict__ rel, float* __restrict__ y) {
  const int bi = blockIdx.y;
  const int Hsp = (bi == 2) ? 4 : 2;
  const int Wsp = (bi == 2) ? 2 : 4;
  const int nH = RES / Hsp, nW = RES / Wsp;
  const int wid = blockIdx.x;     // 0..4095
  const int b = wid >> 11;        // 2048 windows per batch image
  const int r = wid & 2047;
  const int w0 = r % nW;
  const int r2 = r / nW;
  const int h0 = r2 % nH;
  const int d0 = r2 / nH;

  __shared__ float qs[16][97], ks[16][97], vs[16][97];
  const int tid = threadIdx.x;
  for (int idx = tid; idx < 16 * 24; idx += 64) {
    int n = idx / 24, c0 = (idx % 24) * 4;
    int dd = n >> 3, hh = (n / Wsp) % Hsp, ww = n % Wsp;   // Hsp*Wsp==8 both shapes
    int l = ((d0 * 2 + dd) * RES + (h0 * Hsp + hh)) * RES + (w0 * Wsp + ww);
    size_t base = ((size_t)(b * LTOK + l)) * NQKV + bi * 96 + c0;
    u16x4 q4 = *(const u16x4*)(qkv + base);
    u16x4 k4 = *(const u16x4*)(qkv + base + 288);
    u16x4 v4 = *(const u16x4*)(qkv + base + 576);
#pragma unroll
    for (int j = 0; j < 4; j++) {
      qs[n][c0 + j] = bf2f(q4[j]);
      ks[n][c0 + j] = bf2f(k4[j]);
      vs[n][c0 + j] = bf2f(v4[j]);
    }
  }
  __syncthreads();

  const int head = tid >> 4, n = tid & 15;
  const float scale = 0.20412414523193154f;  // 1/sqrt(24)
  float s[16], mx = -1e30f;
#pragma unroll
  for (int m = 0; m < 16; m++) {
    float acc = 0.f;
#pragma unroll
    for (int e = 0; e < 24; e++) acc += qs[n][head * 24 + e] * ks[m][head * 24 + e];
    acc = acc * scale + ptab[(bi * 63 + rel[(bi * 16 + n) * 16 + m]) * 4 + head];
    s[m] = acc;
    mx = fmaxf(mx, acc);
  }
  float sum = 0.f;
#pragma unroll
  for (int m = 0; m < 16; m++) { s[m] = expf(s[m] - mx); sum += s[m]; }
  const float inv = 1.f / sum;

  int dd = n >> 3, hh = (n / Wsp) % Hsp, ww = n % Wsp;
  int l = ((d0 * 2 + dd) * RES + (h0 * Hsp + hh)) * RES + (w0 * Wsp + ww);
  float* yp = y + ((size_t)(b * LTOK + l)) * CDIM + bi * 96 + head * 24;
#pragma unroll
  for (int e = 0; e < 24; e++) {
    float acc = 0.f;
#pragma unroll
    for (int m = 0; m < 16; m++) acc += s[m] * vs[m][head * 24 + e];
    yp[e] = acc * inv;
  }
}

// ---------------- depthwise 3x3x3 conv on V (bf16), added into y ----------------
// LDS-tiled: one block = 8x8x8 token tile x 32 channels.
// Halo 10x10x10 tokens staged in LDS as bf16, token stride 40 u16 (80 B):
//   16B aligned; lane bank-start = (20*w + 8*h) mod 32 -> even 8-way spread for
//   ds_read_b128 (structural minimum). 78.1 KiB LDS -> 2 blocks/CU.
// Weights are wave-uniform scalar loads (K$-cached). Each thread owns tokens
// (d,h,w) and (d+4,h,w): 64 f32 accumulators, then coalesced float4 RMW on y.
__global__ __launch_bounds__(256) void conv_tile_kernel(
    const u16* __restrict__ qkv, const float* __restrict__ cw,
    const float* __restrict__ cb, float* __restrict__ y) {
  __shared__ __align__(16) u16 vs[1000 * 40];   // 80000 B
  const int tid = threadIdx.x;
  const int bx = blockIdx.x;           // 0..127 : b*64 + tile
  const int c0 = blockIdx.y * 32;      // channel group 0..8
  const int b = bx >> 6;
  const int t = bx & 63;
  const int td = (t >> 4) * 8, th = ((t >> 2) & 3) * 8, tw = (t & 3) * 8;

  // ---- stage V halo tile (10x10x10 tokens x 32 ch bf16) ----
#pragma unroll
  for (int p = 0; p < 16; p++) {
    int idx = p * 256 + tid;           // 4 chunks of 16B per token
    if (idx < 4000) {
      int tok = idx >> 2, chunk = idx & 3;
      int dz = tok / 100, rem = tok - dz * 100;
      int hz = rem / 10, wz = rem - hz * 10;
      int d = td + dz - 1, h = th + hz - 1, w = tw + wz - 1;
      uint4 v = make_uint4(0u, 0u, 0u, 0u);
      if ((unsigned)d < 32u && (unsigned)h < 32u && (unsigned)w < 32u)
        v = *(const uint4*)(qkv +
              ((size_t)(b * LTOK + ((d * 32 + h) * 32 + w))) * NQKV + 576 + c0 + chunk * 8);
      *(uint4*)&vs[tok * 40 + chunk * 8] = v;
    }
  }
  __syncthreads();

  // ---- compute: thread owns tokens (d,h,w) and (d+4,h,w) ----
  const int d = tid >> 6, h = (tid >> 3) & 7, w = tid & 7;
  float acc0[32], acc1[32];
#pragma unroll
  for (int c = 0; c < 32; c++) { float bc = cb[c0 + c]; acc0[c] = bc; acc1[c] = bc; }

  for (int kd = 0; kd < 3; kd++) {
#pragma unroll
    for (int kh = 0; kh < 3; kh++) {
#pragma unroll
      for (int kw = 0; kw < 3; kw++) {
        const int k = kd * 9 + kh * 3 + kw;
        // halo-space coord = local + tap (origin at -1)
        const u16* p0 = &vs[(((d + kd) * 100 + (h + kh) * 10) + (w + kw)) * 40];
#pragma unroll
        for (int cq = 0; cq < 4; cq++) {
          uint4 v0 = *(const uint4*)(p0 + cq * 8);
          uint4 v1 = *(const uint4*)(p0 + 16000 + cq * 8);   // (d+4): +4*100*40 u16
          const unsigned* u0 = (const unsigned*)&v0;
          const unsigned* u1 = (const unsigned*)&v1;
#pragma unroll
          for (int j = 0; j < 4; j++) {
            const int ce = cq * 8 + j * 2;
            const float wl = cw[(size_t)(c0 + ce) * 27 + k];       // uniform -> s_load
            const float wh = cw[(size_t)(c0 + ce + 1) * 27 + k];
            acc0[ce]     += bflo(u0[j]) * wl;
            acc0[ce + 1] += bfhi(u0[j]) * wh;
            acc1[ce]     += bflo(u1[j]) * wl;
            acc1[ce + 1] += bfhi(u1[j]) * wh;
          }
        }
      }
    }
  }

  // ---- coalesced float4 read-modify-write into y ----
  const int gl0 = ((td + d) * 32 + (th + h)) * 32 + (tw + w);
  float4* y0 = (float4*)&y[((size_t)(b * LTOK + gl0)) * CDIM + c0];
  float4* y1 = (float4*)&y[((size_t)(b * LTOK + gl0 + 4096)) * CDIM + c0];  // d+4
#pragma unroll
  for (int q = 0; q < 8; q++) {
    float4 t0 = y0[q];
    t0.x += acc0[q * 4];     t0.y += acc0[q * 4 + 1];
    t0.z += acc0[q * 4 + 2]; t0.w += acc0[q * 4 + 3];
    y0[q] = t0;
    float4 t1 = y1[q];
    t1.x += acc1[q * 4];     t1.y += acc1[q * 4 + 1];
    t1.z += acc1[q * 4 + 2]; t1.w += acc1[q * 4 + 3];
    y1[q] = t1;
  }
}

extern "C" void kernel_launch(void* const* d_in, const int* in_sizes, int n_in,
                              void* d_out, int out_size, void* d_ws, size_t ws_size,
                              hipStream_t stream) {
  const float* x      = (const float*)d_in[0];
  // d_in[1..3] = D,H,W scalars (fixed 32)
  const float* w_qkv  = (const float*)d_in[4];
  const float* w_proj = (const float*)d_in[5];
  const float* b_proj = (const float*)d_in[6];
  const float* conv_w = (const float*)d_in[7];
  const float* conv_b = (const float*)d_in[8];
  const float* pos_w  = (const float*)d_in[9];
  const float* pos_b  = (const float*)d_in[10];
  const float* ln1_g  = (const float*)d_in[11];
  const float* ln1_b  = (const float*)d_in[12];
  const float* lin1_w = (const float*)d_in[13];
  const float* lin1_b = (const float*)d_in[14];
  const float* ln2_g  = (const float*)d_in[15];
  const float* ln2_b  = (const float*)d_in[16];
  const float* lin2_w = (const float*)d_in[17];
  const float* lin2_b = (const float*)d_in[18];
  const float* ln3_g  = (const float*)d_in[19];
  const float* ln3_b  = (const float*)d_in[20];
  const float* lin3_w = (const float*)d_in[21];
  const float* lin3_b = (const float*)d_in[22];
  const float* rpe    = (const float*)d_in[23];
  const int*   rel    = (const int*)d_in[24];
  float* out = (float*)d_out;

  // ws layout:
  //   [0, Q)              qkv (bf16), Q = 65536*864*2  -- dead after conv
  //   [Q, +497664)        wqt: w_qkv^T bf16 (864 x 288)
  //   [.., +165888)       wpt: w_proj^T bf16 (288 x 288)
  //   [.., +3024)         ptab f32
  //   big-ws path: ybuf f32 (75.5 MB) after ptab -> proj GEMM writes d_out, no memcpy
  //   small-ws fallback: y in d_out, stage f32 reuses dead qkv region + memcpy back
  const size_t Q = (size_t)MROWS * NQKV * sizeof(u16);
  u16* qkv   = (u16*)d_ws;
  u16* wqt   = (u16*)((char*)d_ws + Q);
  u16* wpt   = (u16*)((char*)d_ws + Q + 497664);
  float* ptab  = (float*)((char*)d_ws + Q + 497664 + 165888);
  float* stage = (float*)d_ws;

  const size_t ybytes = (size_t)MROWS * CDIM * sizeof(float);
  const size_t yoff = (Q + 497664 + 165888 + 3024 + 255) & ~(size_t)255;
  const bool big = ws_size >= yoff + ybytes;
  float* ybuf = big ? (float*)((char*)d_ws + yoff) : out;

  // 0. weight transpose+convert (tiny)
  transpose_cvt<<<(NQKV * CDIM + 255) / 256, 256, 0, stream>>>(w_qkv, wqt, CDIM, NQKV);
  transpose_cvt<<<(CDIM * CDIM + 255) / 256, 256, 0, stream>>>(w_proj, wpt, CDIM, CDIM);
  // 1. qkv = bf16(x @ w_qkv)   (MFMA; NX=7 col tiles, 512 row tiles, XCD-swizzled)
  gemm_mfma<true><<<7 * 512, 256, 0, stream>>>(x, wqt, nullptr, qkv, NQKV, CDIM, 7);
  // 2. rpe bias tables (tiny)
  rpe_mlp<<<1, 256, 0, stream>>>(rpe, pos_w, pos_b, ln1_g, ln1_b, lin1_w, lin1_b,
                                 ln2_g, ln2_b, lin2_w, lin2_b, ln3_g, ln3_b,
                                 lin3_w, lin3_b, ptab);
  // 3. windowed attention -> ybuf (fully overwritten)
  attn_kernel<<<dim3(4096, 3), 64, 0, stream>>>(qkv, ptab, rel, ybuf);
  // 4. ybuf += depthwise_conv3d(V)   (LDS-tiled, 128 tiles x 9 channel groups)
  conv_tile_kernel<<<dim3(128, 9), 256, 0, stream>>>(qkv, conv_w, conv_b, ybuf);
  // 5. out = ybuf @ w_proj + b_proj
  if (big) {
    gemm_mfma<false><<<3 * 512, 256, 0, stream>>>(ybuf, wpt, b_proj, out, CDIM, CDIM, 3);
  } else {
    gemm_mfma<false><<<3 * 512, 256, 0, stream>>>(out, wpt, b_proj, stage, CDIM, CDIM, 3);
    hipMemcpyAsync(out, stage, ybytes, hipMemcpyDeviceToDevice, stream);
  }
}

// Round 2
// 435.834 us; speedup vs baseline: 1.2108x; 1.0818x over previous
//
#include <hip/hip_runtime.h>
#include <hip/hip_bf16.h>
#include <math.h>

#define BATCH 2
#define RES   32
#define LTOK  32768          // RES^3
#define CDIM  288
#define NQKV  864
#define MROWS 65536          // BATCH*LTOK

typedef unsigned short u16;
typedef u16   u16x4 __attribute__((ext_vector_type(4)));
typedef short s16x8 __attribute__((ext_vector_type(8)));   // 8 bf16 in 4 VGPRs (MFMA A/B frag)
typedef float f32x4 __attribute__((ext_vector_type(4)));   // MFMA C/D frag

__device__ __forceinline__ u16 f2bf(float f) {
  union { __hip_bfloat16 h; u16 u; } x;
  x.h = __float2bfloat16(f);
  return x.u;
}
__device__ __forceinline__ float bf2f(u16 u) {
  union { u16 u; __hip_bfloat16 h; } x;
  x.u = u;
  return __bfloat162float(x.h);
}
// bf16 pair unpack from packed u32 (lo = even channel, hi = odd channel)
__device__ __forceinline__ float bflo(unsigned u) {
  union { unsigned u; float f; } x; x.u = u << 16; return x.f;
}
__device__ __forceinline__ float bfhi(unsigned u) {
  union { unsigned u; float f; } x; x.u = u & 0xffff0000u; return x.f;
}

// async 16B global->LDS copy (per-lane global src, wave-uniform LDS base + lane*16)
#define ASYNC16(gsrc, ldst)                                                        \
  __builtin_amdgcn_global_load_lds(                                                \
      (const __attribute__((address_space(1))) void*)(gsrc),                       \
      (__attribute__((address_space(3))) void*)(ldst), 16, 0, 0)

// ---------------- weight transpose+convert: W (K x N) f32 -> Wt (N x K) bf16 ----------------
__global__ __launch_bounds__(256) void transpose_cvt(
    const float* __restrict__ w, u16* __restrict__ wt, int K, int N) {
  int o = blockIdx.x * 256 + threadIdx.x;
  if (o >= N * K) return;
  int n = o / K, k = o - n * K;
  wt[o] = f2bf(w[(size_t)k * N + n]);
}

// ---------------- A-resident stream-N MFMA GEMM ----------------
// out(M x N) = A(M x 288) @ Bt(N x 288)^T (+bias).  K = 288 fixed.
// One block = 64 A-rows, staged ONCE into granule-major LDS [36][64][16B]
// (ds_read bank-start = 4*row mod 32 -> 2 lanes/bank = conflict-free).
// Then loop all N in 32-col chunks; B chunk [36][32][16B] double-buffered via
// global_load_lds(16B) with counted vmcnt(4) (the 4 newest VMEM = this chunk's
// stores) + raw s_barrier -- no vmcnt(0) drain in the main loop.
// 512 thr / 8 waves (4M x 2N of 16x16 frags), LDS 72 KiB -> 2 blocks/CU.
template <bool BF16OUT, bool ABF16>
__global__ __launch_bounds__(512) void gemm_stream(
    const void* __restrict__ Ax, const u16* __restrict__ Bt,
    const float* __restrict__ bias, void* __restrict__ out, int N) {
  __shared__ __align__(16) u16 lds[36864];  // A:[0,18432) B0:[18432,27648) B1:[27648,36864)
  const int bm = blockIdx.x * 64;
  const int tid = threadIdx.x;
  const int lane = tid & 63, wave = tid >> 6;
  const int m16 = lane & 15, kq = lane >> 4;
  const int wm = (wave >> 1) * 16, wn = (wave & 1) * 16;
  const int NC = N >> 5;                    // 32-col chunks

  // ---- A prologue: stage 64 x 288 bf16 into [36][64][16B] ----
  if (ABF16) {
    const u16* Ab = (const u16*)Ax;
    for (int g = wave; g < 36; g += 8)      // one granule = 64 rows x 16B = 1 wave-load
      ASYNC16(Ab + (size_t)(bm + lane) * 288 + g * 8, &lds[g * 512]);
  } else {
    const float* Af = (const float*)Ax;
#pragma unroll
    for (int p = 0; p < 9; p++) {           // 4608 float4 / 512 thr = 9
      int s = p * 512 + tid;
      int g2 = s >> 7, r2 = (s & 127) >> 1, half = s & 1;
      float4 v = *(const float4*)(Af + (size_t)(bm + r2) * 288 + g2 * 8 + half * 4);
      u16x4 pk;
      pk[0] = f2bf(v.x); pk[1] = f2bf(v.y); pk[2] = f2bf(v.z); pk[3] = f2bf(v.w);
      *(u16x4*)&lds[g2 * 512 + r2 * 8 + half * 4] = pk;   // contiguous per wave: no conflicts
    }
  }
  // ---- B chunk 0 into buf0 ----
  {
    const int r = lane & 31, gh = lane >> 5;
    for (int gp = wave; gp < 18; gp += 8)
      ASYNC16(Bt + (size_t)r * 288 + (gp * 2 + gh) * 8, &lds[18432 + gp * 512]);
  }
  asm volatile("s_waitcnt vmcnt(0) lgkmcnt(0)" ::: "memory");
  __builtin_amdgcn_s_barrier();

  int buf = 0;
  for (int c = 0; c < NC; c++) {
    // stage next chunk into the other buffer (reads of it finished 2 chunks ago)
    if (c + 1 < NC) {
      const u16* Bc = Bt + (size_t)(c + 1) * 32 * 288;
      const int r = lane & 31, gh = lane >> 5;
      const int bb0 = 18432 + (buf ^ 1) * 9216;
      for (int gp = wave; gp < 18; gp += 8)
        ASYNC16(Bc + (size_t)r * 288 + (gp * 2 + gh) * 8, &lds[bb0 + gp * 512]);
    }
    __builtin_amdgcn_sched_barrier(0);      // all loads strictly precede the stores (vmcnt count)

    f32x4 acc = {0.f, 0.f, 0.f, 0.f};
    const u16* bb = &lds[18432 + buf * 9216];
#pragma unroll
    for (int ks = 0; ks < 9; ks++) {
      const int g = ks * 4 + kq;
      s16x8 af = *(const s16x8*)&lds[g * 512 + (wm + m16) * 8];
      s16x8 bf = *(const s16x8*)&bb[g * 256 + (wn + m16) * 8];
      acc = __builtin_amdgcn_mfma_f32_16x16x32_bf16(af, bf, acc, 0, 0, 0);
    }
    const int col = (c << 5) + wn + m16;
    const size_t r0 = (size_t)(bm + wm + kq * 4);
    if (BF16OUT) {
      u16* op = (u16*)out;
#pragma unroll
      for (int r = 0; r < 4; r++) op[(r0 + r) * N + col] = f2bf(acc[r]);
    } else {
      const float bv = bias ? bias[col] : 0.f;
      float* op = (float*)out;
#pragma unroll
      for (int r = 0; r < 4; r++) op[(r0 + r) * N + col] = acc[r] + bv;
    }
    if (c + 1 < NC) {
      asm volatile("s_waitcnt vmcnt(4)" ::: "memory");   // next-B loads done; stores may fly
      __builtin_amdgcn_s_barrier();
    }
    buf ^= 1;
  }
}

// ---------------- tiny RPE-bias MLP: (3,63,3) -> (3,63,4) ----------------
__device__ __forceinline__ void ln_relu6(const float* x, float* o,
                                         const float* g, const float* b) {
  float m = 0.f;
#pragma unroll
  for (int i = 0; i < 6; i++) m += x[i];
  m *= (1.f / 6.f);
  float v = 0.f;
#pragma unroll
  for (int i = 0; i < 6; i++) { float d = x[i] - m; v += d * d; }
  v *= (1.f / 6.f);
  float r = rsqrtf(v + 1e-5f);
#pragma unroll
  for (int i = 0; i < 6; i++) {
    float t = (x[i] - m) * r * g[i] + b[i];
    o[i] = t > 0.f ? t : 0.f;
  }
}

__global__ __launch_bounds__(256) void rpe_mlp(
    const float* __restrict__ rpe, const float* __restrict__ pw, const float* __restrict__ pb,
    const float* __restrict__ g1, const float* __restrict__ b1,
    const float* __restrict__ w1, const float* __restrict__ bb1,
    const float* __restrict__ g2, const float* __restrict__ b2,
    const float* __restrict__ w2, const float* __restrict__ bb2,
    const float* __restrict__ g3, const float* __restrict__ b3,
    const float* __restrict__ w3, const float* __restrict__ bb3,
    float* __restrict__ ptab) {
  int t = blockIdx.x * blockDim.x + threadIdx.x;
  if (t >= 3 * 63) return;
  int bi = t / 63, row = t % 63;
  float p[6], q[6];
#pragma unroll
  for (int j = 0; j < 6; j++) {
    float s = pb[bi * 6 + j];
#pragma unroll
    for (int i = 0; i < 3; i++) s += rpe[(bi * 63 + row) * 3 + i] * pw[(bi * 3 + i) * 6 + j];
    p[j] = s;
  }
  ln_relu6(p, q, g1 + bi * 6, b1 + bi * 6);
#pragma unroll
  for (int j = 0; j < 6; j++) {
    float s = bb1[bi * 6 + j];
#pragma unroll
    for (int i = 0; i < 6; i++) s += q[i] * w1[(bi * 6 + i) * 6 + j];
    p[j] = s;
  }
  ln_relu6(p, q, g2 + bi * 6, b2 + bi * 6);
#pragma unroll
  for (int j = 0; j < 6; j++) {
    float s = bb2[bi * 6 + j];
#pragma unroll
    for (int i = 0; i < 6; i++) s += q[i] * w2[(bi * 6 + i) * 6 + j];
    p[j] = s;
  }
  ln_relu6(p, q, g3 + bi * 6, b3 + bi * 6);
#pragma unroll
  for (int h = 0; h < 4; h++) {
    float s = bb3[bi * 4 + h];
#pragma unroll
    for (int i = 0; i < 6; i++) s += q[i] * w3[(bi * 6 + i) * 4 + h];
    ptab[(bi * 63 + row) * 4 + h] = s;
  }
}

// ---------------- windowed attention: one wave per window ----------------
// qkv layout (bf16): (b*L, 864) with column = s*288 + bi*96 + c.  y (f32): (b*L, 288).
__global__ __launch_bounds__(64) void attn_kernel(
    const u16* __restrict__ qkv, const float* __restrict__ ptab,
    const int* __restrict__ rel, float* __restrict__ y) {
  const int bi = blockIdx.y;
  const int Hsp = (bi == 2) ? 4 : 2;
  const int Wsp = (bi == 2) ? 2 : 4;
  const int nH = RES / Hsp, nW = RES / Wsp;
  const int wid = blockIdx.x;     // 0..4095
  const int b = wid >> 11;        // 2048 windows per batch image
  const int r = wid & 2047;
  const int w0 = r % nW;
  const int r2 = r / nW;
  const int h0 = r2 % nH;
  const int d0 = r2 / nH;

  __shared__ float qs[16][97], ks[16][97], vs[16][97];
  const int tid = threadIdx.x;
  for (int idx = tid; idx < 16 * 24; idx += 64) {
    int n = idx / 24, c0 = (idx % 24) * 4;
    int dd = n >> 3, hh = (n / Wsp) % Hsp, ww = n % Wsp;   // Hsp*Wsp==8 both shapes
    int l = ((d0 * 2 + dd) * RES + (h0 * Hsp + hh)) * RES + (w0 * Wsp + ww);
    size_t base = ((size_t)(b * LTOK + l)) * NQKV + bi * 96 + c0;
    u16x4 q4 = *(const u16x4*)(qkv + base);
    u16x4 k4 = *(const u16x4*)(qkv + base + 288);
    u16x4 v4 = *(const u16x4*)(qkv + base + 576);
#pragma unroll
    for (int j = 0; j < 4; j++) {
      qs[n][c0 + j] = bf2f(q4[j]);
      ks[n][c0 + j] = bf2f(k4[j]);
      vs[n][c0 + j] = bf2f(v4[j]);
    }
  }
  __syncthreads();

  const int head = tid >> 4, n = tid & 15;
  const float scale = 0.20412414523193154f;  // 1/sqrt(24)
  float s[16], mx = -1e30f;
#pragma unroll
  for (int m = 0; m < 16; m++) {
    float acc = 0.f;
#pragma unroll
    for (int e = 0; e < 24; e++) acc += qs[n][head * 24 + e] * ks[m][head * 24 + e];
    acc = acc * scale + ptab[(bi * 63 + rel[(bi * 16 + n) * 16 + m]) * 4 + head];
    s[m] = acc;
    mx = fmaxf(mx, acc);
  }
  float sum = 0.f;
#pragma unroll
  for (int m = 0; m < 16; m++) { s[m] = expf(s[m] - mx); sum += s[m]; }
  const float inv = 1.f / sum;

  int dd = n >> 3, hh = (n / Wsp) % Hsp, ww = n % Wsp;
  int l = ((d0 * 2 + dd) * RES + (h0 * Hsp + hh)) * RES + (w0 * Wsp + ww);
  float* yp = y + ((size_t)(b * LTOK + l)) * CDIM + bi * 96 + head * 24;
#pragma unroll
  for (int e = 0; e < 24; e++) {
    float acc = 0.f;
#pragma unroll
    for (int m = 0; m < 16; m++) acc += s[m] * vs[m][head * 24 + e];
    yp[e] = acc * inv;
  }
}

// ---------------- depthwise 3x3x3 conv on V (bf16) ----------------
// LDS-tiled: one block = 8x8x8 token tile x 32 channels, halo 10^3 staged bf16.
// BF16OUT: reads y (f32, attn out), writes y+lcm as bf16 into ybf (proj GEMM A).
// else   : in-place float4 RMW on y (small-ws fallback).
template <bool BF16OUT>
__global__ __launch_bounds__(256) void conv_tile_kernel(
    const u16* __restrict__ qkv, const float* __restrict__ cw,
    const float* __restrict__ cb, float* __restrict__ y, u16* __restrict__ ybf) {
  __shared__ __align__(16) u16 vs[1000 * 40];   // 80000 B
  const int tid = threadIdx.x;
  const int bx = blockIdx.x;           // 0..127 : b*64 + tile
  const int c0 = blockIdx.y * 32;      // channel group 0..8
  const int b = bx >> 6;
  const int t = bx & 63;
  const int td = (t >> 4) * 8, th = ((t >> 2) & 3) * 8, tw = (t & 3) * 8;

  // ---- stage V halo tile (10x10x10 tokens x 32 ch bf16) ----
#pragma unroll
  for (int p = 0; p < 16; p++) {
    int idx = p * 256 + tid;           // 4 chunks of 16B per token
    if (idx < 4000) {
      int tok = idx >> 2, chunk = idx & 3;
      int dz = tok / 100, rem = tok - dz * 100;
      int hz = rem / 10, wz = rem - hz * 10;
      int d = td + dz - 1, h = th + hz - 1, w = tw + wz - 1;
      uint4 v = make_uint4(0u, 0u, 0u, 0u);
      if ((unsigned)d < 32u && (unsigned)h < 32u && (unsigned)w < 32u)
        v = *(const uint4*)(qkv +
              ((size_t)(b * LTOK + ((d * 32 + h) * 32 + w))) * NQKV + 576 + c0 + chunk * 8);
      *(uint4*)&vs[tok * 40 + chunk * 8] = v;
    }
  }
  __syncthreads();

  // ---- compute: thread owns tokens (d,h,w) and (d+4,h,w) ----
  const int d = tid >> 6, h = (tid >> 3) & 7, w = tid & 7;
  float acc0[32], acc1[32];
#pragma unroll
  for (int c = 0; c < 32; c++) { float bc = cb[c0 + c]; acc0[c] = bc; acc1[c] = bc; }

  for (int kd = 0; kd < 3; kd++) {
#pragma unroll
    for (int kh = 0; kh < 3; kh++) {
#pragma unroll
      for (int kw = 0; kw < 3; kw++) {
        const int k = kd * 9 + kh * 3 + kw;
        const u16* p0 = &vs[(((d + kd) * 100 + (h + kh) * 10) + (w + kw)) * 40];
#pragma unroll
        for (int cq = 0; cq < 4; cq++) {
          uint4 v0 = *(const uint4*)(p0 + cq * 8);
          uint4 v1 = *(const uint4*)(p0 + 16000 + cq * 8);   // (d+4): +4*100*40 u16
          const unsigned* u0 = (const unsigned*)&v0;
          const unsigned* u1 = (const unsigned*)&v1;
#pragma unroll
          for (int j = 0; j < 4; j++) {
            const int ce = cq * 8 + j * 2;
            const float wl = cw[(size_t)(c0 + ce) * 27 + k];       // uniform -> s_load
            const float wh = cw[(size_t)(c0 + ce + 1) * 27 + k];
            acc0[ce]     += bflo(u0[j]) * wl;
            acc0[ce + 1] += bfhi(u0[j]) * wh;
            acc1[ce]     += bflo(u1[j]) * wl;
            acc1[ce + 1] += bfhi(u1[j]) * wh;
          }
        }
      }
    }
  }

  const int gl0 = ((td + d) * 32 + (th + h)) * 32 + (tw + w);
  const int t0 = b * LTOK + gl0;
  const int t1 = t0 + 4096;            // d+4

  if (BF16OUT) {
    // y + acc -> bf16 into ybf (4 x uint4 per token)
#pragma unroll
    for (int which = 0; which < 2; which++) {
      const int tt = which ? t1 : t0;
      const float* av = which ? acc1 : acc0;
      const float4* yp = (const float4*)&y[(size_t)tt * CDIM + c0];
      unsigned pk[16];
#pragma unroll
      for (int q = 0; q < 8; q++) {
        float4 cur = yp[q];
        float va = cur.x + av[q * 4],     vb = cur.y + av[q * 4 + 1];
        float vc = cur.z + av[q * 4 + 2], vd = cur.w + av[q * 4 + 3];
        pk[q * 2]     = (unsigned)f2bf(va) | ((unsigned)f2bf(vb) << 16);
        pk[q * 2 + 1] = (unsigned)f2bf(vc) | ((unsigned)f2bf(vd) << 16);
      }
      uint4* op = (uint4*)(ybf + (size_t)tt * CDIM + c0);
#pragma unroll
      for (int q = 0; q < 4; q++) op[q] = ((const uint4*)pk)[q];
    }
  } else {
#pragma unroll
    for (int which = 0; which < 2; which++) {
      const int tt = which ? t1 : t0;
      const float* av = which ? acc1 : acc0;
      float4* yp = (float4*)&y[(size_t)tt * CDIM + c0];
#pragma unroll
      for (int q = 0; q < 8; q++) {
        float4 cur = yp[q];
        cur.x += av[q * 4];     cur.y += av[q * 4 + 1];
        cur.z += av[q * 4 + 2]; cur.w += av[q * 4 + 3];
        yp[q] = cur;
      }
    }
  }
}

extern "C" void kernel_launch(void* const* d_in, const int* in_sizes, int n_in,
                              void* d_out, int out_size, void* d_ws, size_t ws_size,
                              hipStream_t stream) {
  const float* x      = (const float*)d_in[0];
  // d_in[1..3] = D,H,W scalars (fixed 32)
  const float* w_qkv  = (const float*)d_in[4];
  const float* w_proj = (const float*)d_in[5];
  const float* b_proj = (const float*)d_in[6];
  const float* conv_w = (const float*)d_in[7];
  const float* conv_b = (const float*)d_in[8];
  const float* pos_w  = (const float*)d_in[9];
  const float* pos_b  = (const float*)d_in[10];
  const float* ln1_g  = (const float*)d_in[11];
  const float* ln1_b  = (const float*)d_in[12];
  const float* lin1_w = (const float*)d_in[13];
  const float* lin1_b = (const float*)d_in[14];
  const float* ln2_g  = (const float*)d_in[15];
  const float* ln2_b  = (const float*)d_in[16];
  const float* lin2_w = (const float*)d_in[17];
  const float* lin2_b = (const float*)d_in[18];
  const float* ln3_g  = (const float*)d_in[19];
  const float* ln3_b  = (const float*)d_in[20];
  const float* lin3_w = (const float*)d_in[21];
  const float* lin3_b = (const float*)d_in[22];
  const float* rpe    = (const float*)d_in[23];
  const int*   rel    = (const int*)d_in[24];
  float* out = (float*)d_out;

  // ws layout:
  //   [0, Q)         qkv (bf16), Q = 65536*864*2  -- dead after conv
  //   [Q, +497664)   wqt: w_qkv^T bf16 (864 x 288)
  //   [.., +165888)  wpt: w_proj^T bf16 (288 x 288)
  //   [.., +3024)    ptab f32
  //   big path: ybf bf16 (37.7 MB) -> conv writes bf16, proj GEMM async-A path
  //   fallback: conv RMW f32 on d_out; proj GEMM in-place d_out->d_out (A-resident => safe)
  const size_t Q = (size_t)MROWS * NQKV * sizeof(u16);
  u16* qkv   = (u16*)d_ws;
  u16* wqt   = (u16*)((char*)d_ws + Q);
  u16* wpt   = (u16*)((char*)d_ws + Q + 497664);
  float* ptab  = (float*)((char*)d_ws + Q + 497664 + 165888);

  const size_t yoff = (Q + 497664 + 165888 + 3024 + 255) & ~(size_t)255;
  const size_t ybf_bytes = (size_t)MROWS * CDIM * sizeof(u16);
  const bool big = ws_size >= yoff + ybf_bytes;
  u16* ybf = (u16*)((char*)d_ws + yoff);

  // 0. weight transpose+convert (tiny)
  transpose_cvt<<<(NQKV * CDIM + 255) / 256, 256, 0, stream>>>(w_qkv, wqt, CDIM, NQKV);
  transpose_cvt<<<(CDIM * CDIM + 255) / 256, 256, 0, stream>>>(w_proj, wpt, CDIM, CDIM);
  // 1. qkv = bf16(x @ w_qkv)   (A-resident stream-N; A=f32 x, 1024 blocks)
  gemm_stream<true, false><<<MROWS / 64, 512, 0, stream>>>(x, wqt, nullptr, qkv, NQKV);
  // 2. rpe bias tables (tiny)
  rpe_mlp<<<1, 256, 0, stream>>>(rpe, pos_w, pos_b, ln1_g, ln1_b, lin1_w, lin1_b,
                                 ln2_g, ln2_b, lin2_w, lin2_b, ln3_g, ln3_b,
                                 lin3_w, lin3_b, ptab);
  // 3. windowed attention -> d_out (f32, fully overwritten)
  attn_kernel<<<dim3(4096, 3), 64, 0, stream>>>(qkv, ptab, rel, out);
  // 4+5. conv add + projection
  if (big) {
    conv_tile_kernel<true><<<dim3(128, 9), 256, 0, stream>>>(qkv, conv_w, conv_b, out, ybf);
    gemm_stream<false, true><<<MROWS / 64, 512, 0, stream>>>(ybf, wpt, b_proj, out, CDIM);
  } else {
    conv_tile_kernel<false><<<dim3(128, 9), 256, 0, stream>>>(qkv, conv_w, conv_b, out, nullptr);
    gemm_stream<false, false><<<MROWS / 64, 512, 0, stream>>>(out, wpt, b_proj, out, CDIM);
  }
}

// Round 4
// 422.838 us; speedup vs baseline: 1.2480x; 1.0307x over previous
//
#include <hip/hip_runtime.h>
#include <hip/hip_bf16.h>
#include <math.h>

#define BATCH 2
#define RES   32
#define LTOK  32768          // RES^3
#define CDIM  288
#define NQKV  864
#define MROWS 65536          // BATCH*LTOK

typedef unsigned short u16;
typedef u16   u16x4 __attribute__((ext_vector_type(4)));
typedef short s16x8 __attribute__((ext_vector_type(8)));   // 8 bf16 in 4 VGPRs (MFMA A/B frag)
typedef float f32x4 __attribute__((ext_vector_type(4)));   // MFMA C/D frag

__device__ __forceinline__ u16 f2bf(float f) {
  union { __hip_bfloat16 h; u16 u; } x;
  x.h = __float2bfloat16(f);
  return x.u;
}
__device__ __forceinline__ float bf2f(u16 u) {
  union { u16 u; __hip_bfloat16 h; } x;
  x.u = u;
  return __bfloat162float(x.h);
}
// bf16 pair unpack from packed u32 (lo = even channel, hi = odd channel)
__device__ __forceinline__ float bflo(unsigned u) {
  union { unsigned u; float f; } x; x.u = u << 16; return x.f;
}
__device__ __forceinline__ float bfhi(unsigned u) {
  union { unsigned u; float f; } x; x.u = u & 0xffff0000u; return x.f;
}

// async 16B global->LDS copy (per-lane global src, wave-uniform LDS base + lane*16)
#define ASYNC16(gsrc, ldst)                                                        \
  __builtin_amdgcn_global_load_lds(                                                \
      (const __attribute__((address_space(1))) void*)(gsrc),                       \
      (__attribute__((address_space(3))) void*)(ldst), 16, 0, 0)

// ---------------- weight transpose+convert: W (K x N) f32 -> Wt (N x K) bf16 ----------------
__global__ __launch_bounds__(256) void transpose_cvt(
    const float* __restrict__ w, u16* __restrict__ wt, int K, int N) {
  int o = blockIdx.x * 256 + threadIdx.x;
  if (o >= N * K) return;
  int n = o / K, k = o - n * K;
  wt[o] = f2bf(w[(size_t)k * N + n]);
}

// conv weights (C,1,3,3,3) -> k-major [27][288]
__global__ __launch_bounds__(256) void conv_w_kmajor(
    const float* __restrict__ cw, float* __restrict__ wck) {
  int o = blockIdx.x * 256 + threadIdx.x;
  if (o >= 27 * 288) return;
  int k = o / 288, c = o - k * 288;
  wck[o] = cw[c * 27 + k];
}

// ---------------- A-resident stream-N MFMA GEMM ----------------
// out(M x N) = A(M x 288) @ Bt(N x 288)^T (+bias).  K = 288 fixed.
// One block = 64 A-rows staged once; B streamed in 32-col chunks, double-buffered
// via global_load_lds(16B) with counted vmcnt(4) + raw s_barrier.
template <bool BF16OUT, bool ABF16>
__global__ __launch_bounds__(512) void gemm_stream(
    const void* __restrict__ Ax, const u16* __restrict__ Bt,
    const float* __restrict__ bias, void* __restrict__ out, int N) {
  __shared__ __align__(16) u16 lds[36864];  // A:[0,18432) B0:[18432,27648) B1:[27648,36864)
  const int bm = blockIdx.x * 64;
  const int tid = threadIdx.x;
  const int lane = tid & 63, wave = tid >> 6;
  const int m16 = lane & 15, kq = lane >> 4;
  const int wm = (wave >> 1) * 16, wn = (wave & 1) * 16;
  const int NC = N >> 5;                    // 32-col chunks

  // ---- A prologue: stage 64 x 288 bf16 into [36][64][16B] ----
  if (ABF16) {
    const u16* Ab = (const u16*)Ax;
    for (int g = wave; g < 36; g += 8)      // one granule = 64 rows x 16B = 1 wave-load
      ASYNC16(Ab + (size_t)(bm + lane) * 288 + g * 8, &lds[g * 512]);
  } else {
    const float* Af = (const float*)Ax;
#pragma unroll
    for (int p = 0; p < 9; p++) {           // 4608 float4 / 512 thr = 9
      int s = p * 512 + tid;
      int g2 = s >> 7, r2 = (s & 127) >> 1, half = s & 1;
      float4 v = *(const float4*)(Af + (size_t)(bm + r2) * 288 + g2 * 8 + half * 4);
      u16x4 pk;
      pk[0] = f2bf(v.x); pk[1] = f2bf(v.y); pk[2] = f2bf(v.z); pk[3] = f2bf(v.w);
      *(u16x4*)&lds[g2 * 512 + r2 * 8 + half * 4] = pk;   // contiguous per wave: no conflicts
    }
  }
  // ---- B chunk 0 into buf0 ----
  {
    const int r = lane & 31, gh = lane >> 5;
    for (int gp = wave; gp < 18; gp += 8)
      ASYNC16(Bt + (size_t)r * 288 + (gp * 2 + gh) * 8, &lds[18432 + gp * 512]);
  }
  asm volatile("s_waitcnt vmcnt(0) lgkmcnt(0)" ::: "memory");
  __builtin_amdgcn_s_barrier();

  int buf = 0;
  for (int c = 0; c < NC; c++) {
    // stage next chunk into the other buffer (reads of it finished 2 chunks ago)
    if (c + 1 < NC) {
      const u16* Bc = Bt + (size_t)(c + 1) * 32 * 288;
      const int r = lane & 31, gh = lane >> 5;
      const int bb0 = 18432 + (buf ^ 1) * 9216;
      for (int gp = wave; gp < 18; gp += 8)
        ASYNC16(Bc + (size_t)r * 288 + (gp * 2 + gh) * 8, &lds[bb0 + gp * 512]);
    }
    __builtin_amdgcn_sched_barrier(0);      // all loads strictly precede the stores (vmcnt count)

    f32x4 acc = {0.f, 0.f, 0.f, 0.f};
    const u16* bb = &lds[18432 + buf * 9216];
#pragma unroll
    for (int ks = 0; ks < 9; ks++) {
      const int g = ks * 4 + kq;
      s16x8 af = *(const s16x8*)&lds[g * 512 + (wm + m16) * 8];
      s16x8 bf = *(const s16x8*)&bb[g * 256 + (wn + m16) * 8];
      acc = __builtin_amdgcn_mfma_f32_16x16x32_bf16(af, bf, acc, 0, 0, 0);
    }
    const int col = (c << 5) + wn + m16;
    const size_t r0 = (size_t)(bm + wm + kq * 4);
    if (BF16OUT) {
      u16* op = (u16*)out;
#pragma unroll
      for (int r = 0; r < 4; r++) op[(r0 + r) * N + col] = f2bf(acc[r]);
    } else {
      const float bv = bias ? bias[col] : 0.f;
      float* op = (float*)out;
#pragma unroll
      for (int r = 0; r < 4; r++) op[(r0 + r) * N + col] = acc[r] + bv;
    }
    if (c + 1 < NC) {
      asm volatile("s_waitcnt vmcnt(4)" ::: "memory");   // next-B loads done; stores may fly
      __builtin_amdgcn_s_barrier();
    }
    buf ^= 1;
  }
}

// ---------------- tiny RPE-bias MLP: (3,63,3) -> (3,63,4) ----------------
__device__ __forceinline__ void ln_relu6(const float* x, float* o,
                                         const float* g, const float* b) {
  float m = 0.f;
#pragma unroll
  for (int i = 0; i < 6; i++) m += x[i];
  m *= (1.f / 6.f);
  float v = 0.f;
#pragma unroll
  for (int i = 0; i < 6; i++) { float d = x[i] - m; v += d * d; }
  v *= (1.f / 6.f);
  float r = rsqrtf(v + 1e-5f);
#pragma unroll
  for (int i = 0; i < 6; i++) {
    float t = (x[i] - m) * r * g[i] + b[i];
    o[i] = t > 0.f ? t : 0.f;
  }
}

__global__ __launch_bounds__(256) void rpe_mlp(
    const float* __restrict__ rpe, const float* __restrict__ pw, const float* __restrict__ pb,
    const float* __restrict__ g1, const float* __restrict__ b1,
    const float* __restrict__ w1, const float* __restrict__ bb1,
    const float* __restrict__ g2, const float* __restrict__ b2,
    const float* __restrict__ w2, const float* __restrict__ bb2,
    const float* __restrict__ g3, const float* __restrict__ b3,
    const float* __restrict__ w3, const float* __restrict__ bb3,
    float* __restrict__ ptab) {
  int t = blockIdx.x * blockDim.x + threadIdx.x;
  if (t >= 3 * 63) return;
  int bi = t / 63, row = t % 63;
  float p[6], q[6];
#pragma unroll
  for (int j = 0; j < 6; j++) {
    float s = pb[bi * 6 + j];
#pragma unroll
    for (int i = 0; i < 3; i++) s += rpe[(bi * 63 + row) * 3 + i] * pw[(bi * 3 + i) * 6 + j];
    p[j] = s;
  }
  ln_relu6(p, q, g1 + bi * 6, b1 + bi * 6);
#pragma unroll
  for (int j = 0; j < 6; j++) {
    float s = bb1[bi * 6 + j];
#pragma unroll
    for (int i = 0; i < 6; i++) s += q[i] * w1[(bi * 6 + i) * 6 + j];
    p[j] = s;
  }
  ln_relu6(p, q, g2 + bi * 6, b2 + bi * 6);
#pragma unroll
  for (int j = 0; j < 6; j++) {
    float s = bb2[bi * 6 + j];
#pragma unroll
    for (int i = 0; i < 6; i++) s += q[i] * w2[(bi * 6 + i) * 6 + j];
    p[j] = s;
  }
  ln_relu6(p, q, g3 + bi * 6, b3 + bi * 6);
#pragma unroll
  for (int h = 0; h < 4; h++) {
    float s = bb3[bi * 4 + h];
#pragma unroll
    for (int i = 0; i < 6; i++) s += q[i] * w3[(bi * 6 + i) * 4 + h];
    ptab[(bi * 63 + row) * 4 + h] = s;
  }
}

// ---------------- windowed attention via MFMA: one wave per window ----------------
// Per (window, head): scores = mfma(Qfrag, Kfrag) [K=32, ch 24..31 zero-padded];
// softmax across the 16 lanes of a quad (shfl_xor), division deferred to epilogue;
// PV with V^T in LDS; P split hi+lo bf16 packed into k=16..31 (V cols duplicated
// there) -> ~f32-precision P at no extra MFMA cost.
// LDS rows padded to 40 u16 (80 B): frag bank-start spread -> conflict-free b128.
__global__ __launch_bounds__(64) void attn_kernel(
    const u16* __restrict__ qkv, const float* __restrict__ ptab,
    const int* __restrict__ rel, float* __restrict__ y) {
  const int bi = blockIdx.y;
  const int wsh = (bi == 2) ? 1 : 2;            // log2(Wsp)
  const int hsh = (bi == 2) ? 2 : 1;            // log2(Hsp)
  const int Wm1 = (1 << wsh) - 1, Hm1 = (1 << hsh) - 1;
  const int nW = RES >> wsh, nH = RES >> hsh;
  const int wid = blockIdx.x;     // 0..4095
  const int b = wid >> 11;
  const int r_ = wid & 2047;
  const int w0 = r_ % nW;
  const int r2 = r_ / nW;
  const int h0 = r2 % nH;
  const int d0 = r2 / nH;

  __shared__ __align__(16) u16 sq[16 * 40];     // [n][k]  k: 0..23 data, 24..31 zero, 32..39 unused
  __shared__ __align__(16) u16 sk[16 * 40];
  __shared__ __align__(16) u16 svt[32 * 40];    // [ch][m] cols 0..15 = V^T, 16..31 dup; rows 24..31 zero
  __shared__ __align__(16) u16 sps[16 * 40];    // [n][m]  m: 0..15 hi, 16..31 lo

  const int lane = threadIdx.x;
  const int m16 = lane & 15, q4 = lane >> 4;

  // ---- zero-init ALL of sq/sk/svt (full coverage, 16B-aligned chunks) ----
  {
    uint4 z = make_uint4(0u, 0u, 0u, 0u);
#pragma unroll
    for (int i = lane; i < 80; i += 64) {        // 640 u16 = 80 chunks of 8
      *(uint4*)&sq[i * 8] = z;
      *(uint4*)&sk[i * 8] = z;
    }
#pragma unroll
    for (int i = lane; i < 160; i += 64)         // 1280 u16 = 160 chunks of 8
      *(uint4*)&svt[i * 8] = z;
  }
  __syncthreads();   // zeroing must complete before any lane stages data

  // rel gather (head-invariant): rv[r] for n = q4*4+r, m = m16
  int rv[4];
#pragma unroll
  for (int r = 0; r < 4; r++) rv[r] = rel[(bi * 16 + q4 * 4 + r) * 16 + m16];

  // per-row global y bases for n = q4*4+r
  size_t ybase[4];
#pragma unroll
  for (int r = 0; r < 4; r++) {
    int n = q4 * 4 + r;
    int dd = n >> 3, hh2 = (n >> wsh) & Hm1, ww = n & Wm1;
    int l = ((d0 * 2 + dd) * RES + ((h0 << hsh) + hh2)) * RES + ((w0 << wsh) + ww);
    ybase[r] = (size_t)(b * LTOK + l) * CDIM + bi * 96;
  }

  const float scale = 0.20412414523193154f;  // 1/sqrt(24)

  for (int hd = 0; hd < 4; hd++) {
    // ---- stage q,k,v for this head: 16 tokens x 24 ch, u16x4 chunks ----
#pragma unroll
    for (int it = 0; it < 2; it++) {
      int idx = it * 64 + lane;
      if (idx < 96) {
        int n = idx / 6, c4 = idx - n * 6, ch = c4 * 4;
        int dd = n >> 3, hh2 = (n >> wsh) & Hm1, ww = n & Wm1;
        int l = ((d0 * 2 + dd) * RES + ((h0 << hsh) + hh2)) * RES + ((w0 << wsh) + ww);
        size_t base = (size_t)(b * LTOK + l) * NQKV + bi * 96 + hd * 24 + ch;
        u16x4 qv = *(const u16x4*)(qkv + base);
        u16x4 kv = *(const u16x4*)(qkv + base + 288);
        u16x4 vv = *(const u16x4*)(qkv + base + 576);
        *(u16x4*)&sq[n * 40 + ch] = qv;
        *(u16x4*)&sk[n * 40 + ch] = kv;
#pragma unroll
        for (int j = 0; j < 4; j++) {
          svt[(ch + j) * 40 + n] = vv[j];
          svt[(ch + j) * 40 + 16 + n] = vv[j];
        }
      }
    }
    __syncthreads();

    // ---- scores: one MFMA (D: col=m16 -> key m, rows (q4*4+r) -> query n) ----
    s16x8 af = *(const s16x8*)&sq[m16 * 40 + q4 * 8];
    s16x8 bf = *(const s16x8*)&sk[m16 * 40 + q4 * 8];
    f32x4 sc = __builtin_amdgcn_mfma_f32_16x16x32_bf16(af, bf, (f32x4){0.f, 0.f, 0.f, 0.f}, 0, 0, 0);

    float inv[4];
#pragma unroll
    for (int r = 0; r < 4; r++) {
      float s = sc[r] * scale + ptab[(size_t)(bi * 63 + rv[r]) * 4 + hd];
      float mx = s;
#pragma unroll
      for (int msk = 1; msk <= 8; msk <<= 1) mx = fmaxf(mx, __shfl_xor(mx, msk));
      float e = expf(s - mx);
      float sum = e;
#pragma unroll
      for (int msk = 1; msk <= 8; msk <<= 1) sum += __shfl_xor(sum, msk);
      inv[r] = 1.f / sum;
      u16 hi = f2bf(e);
      float lo = e - bf2f(hi);
      sps[(q4 * 4 + r) * 40 + m16] = hi;
      sps[(q4 * 4 + r) * 40 + 16 + m16] = f2bf(lo);
    }
    __syncthreads();

    // ---- PV: 2 MFMAs (A = P hi|lo over k=0..31; B = svt rows: ch 0..15, 16..31) ----
    s16x8 pa = *(const s16x8*)&sps[m16 * 40 + q4 * 8];
    s16x8 v1 = *(const s16x8*)&svt[m16 * 40 + q4 * 8];
    s16x8 v2 = *(const s16x8*)&svt[(16 + m16) * 40 + q4 * 8];
    f32x4 o1 = __builtin_amdgcn_mfma_f32_16x16x32_bf16(pa, v1, (f32x4){0.f, 0.f, 0.f, 0.f}, 0, 0, 0);
    f32x4 o2 = __builtin_amdgcn_mfma_f32_16x16x32_bf16(pa, v2, (f32x4){0.f, 0.f, 0.f, 0.f}, 0, 0, 0);

#pragma unroll
    for (int r = 0; r < 4; r++) {
      float* yp = y + ybase[r] + hd * 24;
      yp[m16] = o1[r] * inv[r];
      if (m16 < 8) yp[16 + m16] = o2[r] * inv[r];
    }
    __syncthreads();
  }
}

// ---------------- depthwise 3x3x3 conv on V (bf16) ----------------
// one block = 8x8x8 token tile x 32 channels, 512 threads (1 token/thread)
// -> 2 blocks/CU x 8 waves = 16 waves/CU: latency-hiding fix.
// Halo 10^3 tokens staged bf16, token stride 40 u16 (80 B, conflict-free spread).
// Weights k-major [27][288]: 32 contiguous floats per tap (uniform s_loads).
template <bool BF16OUT>
__global__ __launch_bounds__(512, 4) void conv_tile_kernel(
    const u16* __restrict__ qkv, const float* __restrict__ wck,
    const float* __restrict__ cb, float* __restrict__ y, u16* __restrict__ ybf) {
  __shared__ __align__(16) u16 vs[1000 * 40];   // 80000 B
  const int tid = threadIdx.x;
  const int bx = blockIdx.x;           // 0..127 : b*64 + tile
  const int c0 = blockIdx.y * 32;      // channel group 0..8
  const int b = bx >> 6;
  const int t = bx & 63;
  const int td = (t >> 4) * 8, th = ((t >> 2) & 3) * 8, tw = (t & 3) * 8;

  // ---- stage V halo tile (10x10x10 tokens x 32 ch bf16) ----
#pragma unroll
  for (int p = 0; p < 8; p++) {
    int idx = p * 512 + tid;           // 4 chunks of 16B per token
    if (idx < 4000) {
      int tok = idx >> 2, chunk = idx & 3;
      int dz = tok / 100, rem = tok - dz * 100;
      int hz = rem / 10, wz = rem - hz * 10;
      int d = td + dz - 1, h = th + hz - 1, w = tw + wz - 1;
      uint4 v = make_uint4(0u, 0u, 0u, 0u);
      if ((unsigned)d < 32u && (unsigned)h < 32u && (unsigned)w < 32u)
        v = *(const uint4*)(qkv +
              ((size_t)(b * LTOK + ((d * 32 + h) * 32 + w))) * NQKV + 576 + c0 + chunk * 8);
      *(uint4*)&vs[tok * 40 + chunk * 8] = v;
    }
  }
  __syncthreads();

  // ---- compute: thread owns token (d,h,w) ----
  const int d = tid >> 6, h = (tid >> 3) & 7, w = tid & 7;
  float acc[32];
#pragma unroll
  for (int c = 0; c < 32; c++) acc[c] = cb[c0 + c];

  for (int kd = 0; kd < 3; kd++) {
#pragma unroll
    for (int kh = 0; kh < 3; kh++) {
#pragma unroll
      for (int kw = 0; kw < 3; kw++) {
        const int k = kd * 9 + kh * 3 + kw;
        const float* wk = wck + k * 288 + c0;   // 32 contiguous uniform floats
        const u16* p0 = &vs[(((d + kd) * 100 + (h + kh) * 10) + (w + kw)) * 40];
#pragma unroll
        for (int cq = 0; cq < 4; cq++) {
          uint4 v0 = *(const uint4*)(p0 + cq * 8);
          const unsigned* u0 = (const unsigned*)&v0;
#pragma unroll
          for (int j = 0; j < 4; j++) {
            const int ce = cq * 8 + j * 2;
            acc[ce]     += bflo(u0[j]) * wk[ce];
            acc[ce + 1] += bfhi(u0[j]) * wk[ce + 1];
          }
        }
      }
    }
  }

  const int tt = b * LTOK + ((td + d) * 32 + (th + h)) * 32 + (tw + w);

  if (BF16OUT) {
    const float4* yp = (const float4*)&y[(size_t)tt * CDIM + c0];
    unsigned pk[16];
#pragma unroll
    for (int q = 0; q < 8; q++) {
      float4 cur = yp[q];
      float va = cur.x + acc[q * 4],     vb = cur.y + acc[q * 4 + 1];
      float vc = cur.z + acc[q * 4 + 2], vd = cur.w + acc[q * 4 + 3];
      pk[q * 2]     = (unsigned)f2bf(va) | ((unsigned)f2bf(vb) << 16);
      pk[q * 2 + 1] = (unsigned)f2bf(vc) | ((unsigned)f2bf(vd) << 16);
    }
    uint4* op = (uint4*)(ybf + (size_t)tt * CDIM + c0);
#pragma unroll
    for (int q = 0; q < 4; q++) op[q] = ((const uint4*)pk)[q];
  } else {
    float4* yp = (float4*)&y[(size_t)tt * CDIM + c0];
#pragma unroll
    for (int q = 0; q < 8; q++) {
      float4 cur = yp[q];
      cur.x += acc[q * 4];     cur.y += acc[q * 4 + 1];
      cur.z += acc[q * 4 + 2]; cur.w += acc[q * 4 + 3];
      yp[q] = cur;
    }
  }
}

extern "C" void kernel_launch(void* const* d_in, const int* in_sizes, int n_in,
                              void* d_out, int out_size, void* d_ws, size_t ws_size,
                              hipStream_t stream) {
  const float* x      = (const float*)d_in[0];
  // d_in[1..3] = D,H,W scalars (fixed 32)
  const float* w_qkv  = (const float*)d_in[4];
  const float* w_proj = (const float*)d_in[5];
  const float* b_proj = (const float*)d_in[6];
  const float* conv_w = (const float*)d_in[7];
  const float* conv_b = (const float*)d_in[8];
  const float* pos_w  = (const float*)d_in[9];
  const float* pos_b  = (const float*)d_in[10];
  const float* ln1_g  = (const float*)d_in[11];
  const float* ln1_b  = (const float*)d_in[12];
  const float* lin1_w = (const float*)d_in[13];
  const float* lin1_b = (const float*)d_in[14];
  const float* ln2_g  = (const float*)d_in[15];
  const float* ln2_b  = (const float*)d_in[16];
  const float* lin2_w = (const float*)d_in[17];
  const float* lin2_b = (const float*)d_in[18];
  const float* ln3_g  = (const float*)d_in[19];
  const float* ln3_b  = (const float*)d_in[20];
  const float* lin3_w = (const float*)d_in[21];
  const float* lin3_b = (const float*)d_in[22];
  const float* rpe    = (const float*)d_in[23];
  const int*   rel    = (const int*)d_in[24];
  float* out = (float*)d_out;

  // ws layout:
  //   [0, Q)         qkv (bf16), Q = 65536*864*2  -- dead after conv
  //   [Q, +497664)   wqt: w_qkv^T bf16 (864 x 288)
  //   [.., +165888)  wpt: w_proj^T bf16 (288 x 288)
  //   [.., +3024)    ptab f32
  //   [.., +31104)   wck f32 (conv weights k-major)
  //   big path: ybf bf16 (37.7 MB) -> conv writes bf16, proj GEMM async-A path
  //   fallback: conv RMW f32 on d_out; proj GEMM in-place d_out->d_out (A-resident => safe)
  const size_t Q = (size_t)MROWS * NQKV * sizeof(u16);
  u16* qkv   = (u16*)d_ws;
  u16* wqt   = (u16*)((char*)d_ws + Q);
  u16* wpt   = (u16*)((char*)d_ws + Q + 497664);
  float* ptab  = (float*)((char*)d_ws + Q + 497664 + 165888);
  float* wck   = (float*)((char*)d_ws + Q + 497664 + 165888 + 3024);

  const size_t yoff = (Q + 497664 + 165888 + 3024 + 31104 + 255) & ~(size_t)255;
  const size_t ybf_bytes = (size_t)MROWS * CDIM * sizeof(u16);
  const bool big = ws_size >= yoff + ybf_bytes;
  u16* ybf = (u16*)((char*)d_ws + yoff);

  // 0. weight transforms (tiny)
  transpose_cvt<<<(NQKV * CDIM + 255) / 256, 256, 0, stream>>>(w_qkv, wqt, CDIM, NQKV);
  transpose_cvt<<<(CDIM * CDIM + 255) / 256, 256, 0, stream>>>(w_proj, wpt, CDIM, CDIM);
  conv_w_kmajor<<<(27 * 288 + 255) / 256, 256, 0, stream>>>(conv_w, wck);
  // 1. qkv = bf16(x @ w_qkv)   (A-resident stream-N; A=f32 x, 1024 blocks)
  gemm_stream<true, false><<<MROWS / 64, 512, 0, stream>>>(x, wqt, nullptr, qkv, NQKV);
  // 2. rpe bias tables (tiny)
  rpe_mlp<<<1, 256, 0, stream>>>(rpe, pos_w, pos_b, ln1_g, ln1_b, lin1_w, lin1_b,
                                 ln2_g, ln2_b, lin2_w, lin2_b, ln3_g, ln3_b,
                                 lin3_w, lin3_b, ptab);
  // 3. windowed attention (MFMA) -> d_out (f32, fully overwritten)
  attn_kernel<<<dim3(4096, 3), 64, 0, stream>>>(qkv, ptab, rel, out);
  // 4+5. conv add + projection
  if (big) {
    conv_tile_kernel<true><<<dim3(128, 9), 512, 0, stream>>>(qkv, wck, conv_b, out, ybf);
    gemm_stream<false, true><<<MROWS / 64, 512, 0, stream>>>(ybf, wpt, b_proj, out, CDIM);
  } else {
    conv_tile_kernel<false><<<dim3(128, 9), 512, 0, stream>>>(qkv, wck, conv_b, out, nullptr);
    gemm_stream<false, false><<<MROWS / 64, 512, 0, stream>>>(out, wpt, b_proj, out, CDIM);
  }
}